// Round 1
// baseline (1765.244 us; speedup 1.0000x reference)
//
#include <hip/hip_runtime.h>
#include <math.h>

// ---------------------------------------------------------------------------
// DevignLite: 3-layer GCN + mean/max pool + MLP head.  All fp32.
// N=100000 nodes, E=1600000 edges, D=64, G=256 graphs.
// Strategy round 0: wave-per-edge atomic scatter; self-loops folded into
// aggregation init; bias+relu fused into the consumer kernel.
// ---------------------------------------------------------------------------

__global__ void k_fill1(float* p, int n) {
  int i = blockIdx.x * blockDim.x + threadIdx.x;
  if (i < n) p[i] = 1.0f;
}

__global__ void k_zero(float* p, int n) {
  int i = blockIdx.x * blockDim.x + threadIdx.x;
  if (i < n) p[i] = 0.0f;
}

// deg[dst] += 1 over real edges (self-loop handled by init to 1.0)
__global__ void k_degcount(const int* __restrict__ dst, float* __restrict__ deg, int E) {
  int e = blockIdx.x * blockDim.x + threadIdx.x;
  if (e < E) atomicAdd(&deg[dst[e]], 1.0f);
}

__global__ void k_dinv(float* p, int n) {
  int i = blockIdx.x * blockDim.x + threadIdx.x;
  if (i < n) p[i] = 1.0f / sqrtf(p[i]);   // deg >= 1 always (self-loop)
}

__global__ void k_norm(const int* __restrict__ src, const int* __restrict__ dst,
                       const float* __restrict__ dinv, float* __restrict__ norm, int E) {
  int e = blockIdx.x * blockDim.x + threadIdx.x;
  if (e < E) norm[e] = dinv[src[e]] * dinv[dst[e]];
}

// x[row] = emb_table[tok[row]] ; 16 float4 per row, 16 threads per row
__global__ void k_embed(const int* __restrict__ tok, const float* __restrict__ emb,
                        float* __restrict__ x, int n) {
  int t = blockIdx.x * blockDim.x + threadIdx.x;
  int row = t >> 4, c = t & 15;
  if (row >= n) return;
  long v = tok[row];
  ((float4*)x)[(long)row * 16 + c] = ((const float4*)emb)[v * 16 + c];
}

// xw = act(xin) @ W.  act = identity (ACT=0) or relu(v + bprev) (ACT=1).
// Block: 256 threads -> 16 rows; thread (ty,tx) computes 4 rows' column tx.
template <bool ACT>
__global__ __launch_bounds__(256) void k_matmul(const float* __restrict__ xin,
                                                const float* __restrict__ W,
                                                const float* __restrict__ bprev,
                                                float* __restrict__ xw, int n) {
  __shared__ float sW[64 * 64];
  __shared__ float sx[16 * 64];
  int tid = threadIdx.x;
  int tx = tid & 63, ty = tid >> 6;
  const float4* W4 = (const float4*)W;
  float4* sW4 = (float4*)sW;
#pragma unroll
  for (int k = 0; k < 4; k++) sW4[k * 256 + tid] = W4[k * 256 + tid];
  long base = (long)blockIdx.x * 16;
  {
    int r = tid >> 4, c4 = tid & 15;
    long row = base + r;
    float4 v = make_float4(0.f, 0.f, 0.f, 0.f);
    if (row < n) v = ((const float4*)xin)[row * 16 + c4];
    if (ACT) {
      float4 bb = ((const float4*)bprev)[c4];
      v.x = fmaxf(v.x + bb.x, 0.f);
      v.y = fmaxf(v.y + bb.y, 0.f);
      v.z = fmaxf(v.z + bb.z, 0.f);
      v.w = fmaxf(v.w + bb.w, 0.f);
    }
    ((float4*)sx)[tid] = v;
  }
  __syncthreads();
  float acc0 = 0.f, acc1 = 0.f, acc2 = 0.f, acc3 = 0.f;
#pragma unroll
  for (int d = 0; d < 64; d++) {
    float w = sW[d * 64 + tx];           // 2-way LDS alias: free
    acc0 += sx[(ty * 4 + 0) * 64 + d] * w;  // wave-uniform: broadcast
    acc1 += sx[(ty * 4 + 1) * 64 + d] * w;
    acc2 += sx[(ty * 4 + 2) * 64 + d] * w;
    acc3 += sx[(ty * 4 + 3) * 64 + d] * w;
  }
  long r0 = base + ty * 4;
  if (r0 + 0 < n) xw[(r0 + 0) * 64 + tx] = acc0;
  if (r0 + 1 < n) xw[(r0 + 1) * 64 + tx] = acc1;
  if (r0 + 2 < n) xw[(r0 + 2) * 64 + tx] = acc2;
  if (r0 + 3 < n) xw[(r0 + 3) * 64 + tx] = acc3;
}

// agg[i] = xw[i] * dinv[i]^2   (self-loop contribution; full overwrite)
__global__ void k_selfinit(const float* __restrict__ xw, const float* __restrict__ dinv,
                           float* __restrict__ agg, int n) {
  int t = blockIdx.x * blockDim.x + threadIdx.x;   // n*16 float4 slots
  int row = t >> 4;
  if (row >= n) return;
  float s = dinv[row];
  s = s * s;
  float4 v = ((const float4*)xw)[t];
  v.x *= s; v.y *= s; v.z *= s; v.w *= s;
  ((float4*)agg)[t] = v;
}

// one wave per edge: agg[dst] += xw[src] * norm
__global__ void k_scatter(const int* __restrict__ src, const int* __restrict__ dst,
                          const float* __restrict__ norm, const float* __restrict__ xw,
                          float* __restrict__ agg, int E) {
  int gt = blockIdx.x * blockDim.x + threadIdx.x;
  int e = gt >> 6, lane = gt & 63;
  if (e >= E) return;
  int s = src[e], t = dst[e];
  float w = norm[e];
  float v = xw[(long)s * 64 + lane] * w;
  atomicAdd(&agg[(long)t * 64 + lane], v);
}

// one wave per node: relu(x+b) -> per-graph sum/max/count
__global__ void k_pool(const float* __restrict__ x, const float* __restrict__ b,
                       const int* __restrict__ batch, float* __restrict__ hsum,
                       float* __restrict__ hmax, int* __restrict__ cnt, int n) {
  int gt = blockIdx.x * blockDim.x + threadIdx.x;
  int i = gt >> 6, lane = gt & 63;
  if (i >= n) return;
  int g = batch[i];
  float v = fmaxf(x[(long)i * 64 + lane] + b[lane], 0.0f);
  atomicAdd(&hsum[g * 64 + lane], v);
  atomicMax((int*)&hmax[g * 64 + lane], __float_as_int(v));  // v>=0: bit-monotone
  if (lane == 0) atomicAdd(&cnt[g], 1);
}

// one block (64 threads) per graph: logits = relu(h@Wc1+bc1)@Wc2+bc2
__global__ __launch_bounds__(64) void k_cls(const float* __restrict__ hsum,
                                            const float* __restrict__ hmax,
                                            const int* __restrict__ cnt,
                                            const float* __restrict__ Wc1,
                                            const float* __restrict__ bc1,
                                            const float* __restrict__ Wc2,
                                            const float* __restrict__ bc2,
                                            float* __restrict__ out) {
  __shared__ float h[128];
  __shared__ float hid[64];
  int g = blockIdx.x, j = threadIdx.x;
  int c = cnt[g];
  float cf = (float)(c > 0 ? c : 1);
  h[j] = hsum[g * 64 + j] / cf;
  h[64 + j] = hmax[g * 64 + j];
  __syncthreads();
  float acc = bc1[j];
  for (int k = 0; k < 128; k++) acc += h[k] * Wc1[k * 64 + j];
  hid[j] = fmaxf(acc, 0.f);
  __syncthreads();
  if (j < 2) {
    float a = bc2[j];
    for (int k = 0; k < 64; k++) a += hid[k] * Wc2[k * 2 + j];
    out[g * 2 + j] = a;
  }
}

extern "C" void kernel_launch(void* const* d_in, const int* in_sizes, int n_in,
                              void* d_out, int out_size, void* d_ws, size_t ws_size,
                              hipStream_t stream) {
  const int N = in_sizes[0];
  const int E = in_sizes[1] / 2;
  const int G = out_size / 2;

  const int* tok   = (const int*)d_in[0];
  const int* ei    = (const int*)d_in[1];
  const int* batch = (const int*)d_in[2];
  const float* emb = (const float*)d_in[3];
  const float* W0 = (const float*)d_in[4];  const float* b0 = (const float*)d_in[5];
  const float* W1 = (const float*)d_in[6];  const float* b1 = (const float*)d_in[7];
  const float* W2 = (const float*)d_in[8];  const float* b2 = (const float*)d_in[9];
  const float* Wc1 = (const float*)d_in[10]; const float* bc1 = (const float*)d_in[11];
  const float* Wc2 = (const float*)d_in[12]; const float* bc2 = (const float*)d_in[13];
  const int* srcp = ei;
  const int* dstp = ei + E;

  float* ws = (float*)d_ws;
  float* dinv = ws;                          // N
  float* norm = dinv + N;                    // E
  float* bufA = norm + E;                    // N*64
  float* bufB = bufA + (size_t)N * 64;       // N*64
  float* bufC = bufB + (size_t)N * 64;       // N*64
  float* hsum = bufC + (size_t)N * 64;       // G*64
  float* hmax = hsum + (size_t)G * 64;       // G*64
  int*   cnt  = (int*)(hmax + (size_t)G * 64); // G

  auto cdiv = [](long a, long b) { return (int)((a + b - 1) / b); };

  // --- gcn_norm ---
  k_fill1<<<cdiv(N, 256), 256, 0, stream>>>(dinv, N);
  k_degcount<<<cdiv(E, 256), 256, 0, stream>>>(dstp, dinv, E);
  k_dinv<<<cdiv(N, 256), 256, 0, stream>>>(dinv, N);
  k_norm<<<cdiv(E, 256), 256, 0, stream>>>(srcp, dstp, dinv, norm, E);

  // --- embedding gather ---
  k_embed<<<cdiv((long)N * 16, 256), 256, 0, stream>>>(tok, emb, bufA, N);

  // --- layer 0: in A (raw), xw B, agg C ---
  k_matmul<false><<<cdiv(N, 16), 256, 0, stream>>>(bufA, W0, nullptr, bufB, N);
  k_selfinit<<<cdiv((long)N * 16, 256), 256, 0, stream>>>(bufB, dinv, bufC, N);
  k_scatter<<<cdiv((long)E * 64, 256), 256, 0, stream>>>(srcp, dstp, norm, bufB, bufC, E);

  // --- layer 1: in C (relu+b0), xw A, agg B ---
  k_matmul<true><<<cdiv(N, 16), 256, 0, stream>>>(bufC, W1, b0, bufA, N);
  k_selfinit<<<cdiv((long)N * 16, 256), 256, 0, stream>>>(bufA, dinv, bufB, N);
  k_scatter<<<cdiv((long)E * 64, 256), 256, 0, stream>>>(srcp, dstp, norm, bufA, bufB, E);

  // --- layer 2: in B (relu+b1), xw C, agg A ---
  k_matmul<true><<<cdiv(N, 16), 256, 0, stream>>>(bufB, W2, b1, bufC, N);
  k_selfinit<<<cdiv((long)N * 16, 256), 256, 0, stream>>>(bufC, dinv, bufA, N);
  k_scatter<<<cdiv((long)E * 64, 256), 256, 0, stream>>>(srcp, dstp, norm, bufC, bufA, E);

  // --- pooling (relu+b2 fused) ---
  k_zero<<<cdiv((long)G * 129, 256), 256, 0, stream>>>(hsum, G * 129);
  k_pool<<<cdiv((long)N * 64, 256), 256, 0, stream>>>(bufA, b2, batch, hsum, hmax, cnt, N);

  // --- classifier head ---
  k_cls<<<G, 64, 0, stream>>>(hsum, hmax, cnt, Wc1, bc1, Wc2, bc2, (float*)d_out);
}

// Round 2
// 829.716 us; speedup vs baseline: 2.1275x; 2.1275x over previous
//
#include <hip/hip_runtime.h>
#include <math.h>

// ---------------------------------------------------------------------------
// DevignLite: 3-layer GCN + mean/max pool + MLP head.  All fp32.
// N=100000 nodes, E=1600000 edges, D=64, G=256 graphs.
// Round 1: kill atomics.
//  - Edge aggregation: build dst-CSR once (histogram + scan + place), then
//    gather-based aggregate (one wave per dst node), self-loop folded in.
//  - Pooling: batch is sorted -> register segment-reduction per wave, one
//    atomic flush per segment boundary instead of per node.
// ---------------------------------------------------------------------------

__global__ void k_zero(float* p, long n) {
  long i = (long)blockIdx.x * blockDim.x + threadIdx.x;
  if (i < n) p[i] = 0.0f;
}

// cnt[dst] += 1 over real edges
__global__ void k_degcount(const int* __restrict__ dst, int* __restrict__ cnt, int E) {
  int e = blockIdx.x * blockDim.x + threadIdx.x;
  if (e < E) atomicAdd(&cnt[dst[e]], 1);
}

// dinv[i] = (1+cnt[i])^-0.5
__global__ void k_dinv(const int* __restrict__ cnt, float* __restrict__ dinv, int n) {
  int i = blockIdx.x * blockDim.x + threadIdx.x;
  if (i < n) dinv[i] = 1.0f / sqrtf((float)(1 + cnt[i]));
}

// ---- 2-level exclusive scan of cnt[N] -> off[N+1] (and cursor copy) ----
__global__ __launch_bounds__(256) void k_scan1(const int* __restrict__ cnt,
                                               int* __restrict__ excl,
                                               int* __restrict__ bsum, int n) {
  __shared__ int s[256];
  int i = blockIdx.x * 256 + threadIdx.x;
  int v = (i < n) ? cnt[i] : 0;
  s[threadIdx.x] = v;
  __syncthreads();
  for (int d = 1; d < 256; d <<= 1) {
    int t = (threadIdx.x >= (unsigned)d) ? s[threadIdx.x - d] : 0;
    __syncthreads();
    s[threadIdx.x] += t;
    __syncthreads();
  }
  if (i < n) excl[i] = s[threadIdx.x] - v;       // exclusive within block
  if (threadIdx.x == 255) bsum[blockIdx.x] = s[255];
}

__global__ __launch_bounds__(512) void k_scan2(int* __restrict__ bsum, int nb) {
  __shared__ int s[512];
  int v = (threadIdx.x < (unsigned)nb) ? bsum[threadIdx.x] : 0;
  s[threadIdx.x] = v;
  __syncthreads();
  for (int d = 1; d < 512; d <<= 1) {
    int t = (threadIdx.x >= (unsigned)d) ? s[threadIdx.x - d] : 0;
    __syncthreads();
    s[threadIdx.x] += t;
    __syncthreads();
  }
  if (threadIdx.x < (unsigned)nb) bsum[threadIdx.x] = s[threadIdx.x] - v;  // exclusive
}

__global__ void k_scan3(int* __restrict__ excl /*in: local excl, out: cursor*/,
                        const int* __restrict__ bsum, int* __restrict__ off,
                        int n, int E) {
  int i = blockIdx.x * 256 + threadIdx.x;
  if (i < n) {
    int o = excl[i] + bsum[blockIdx.x];
    off[i] = o;
    excl[i] = o;                                  // reuse as atomic cursor
  }
  if (i == 0) off[n] = E;
}

// csrc[cursor[dst[e]]++] = src[e]
__global__ void k_place(const int* __restrict__ src, const int* __restrict__ dst,
                        int* __restrict__ cursor, int* __restrict__ csrc, int E) {
  int e = blockIdx.x * blockDim.x + threadIdx.x;
  if (e >= E) return;
  int p = atomicAdd(&cursor[dst[e]], 1);
  csrc[p] = src[e];
}

// x[row] = emb_table[tok[row]] ; 16 float4 per row, 16 threads per row
__global__ void k_embed(const int* __restrict__ tok, const float* __restrict__ emb,
                        float* __restrict__ x, int n) {
  int t = blockIdx.x * blockDim.x + threadIdx.x;
  int row = t >> 4, c = t & 15;
  if (row >= n) return;
  long v = tok[row];
  ((float4*)x)[(long)row * 16 + c] = ((const float4*)emb)[v * 16 + c];
}

// xw = act(xin) @ W.  act = identity (ACT=0) or relu(v + bprev) (ACT=1).
template <bool ACT>
__global__ __launch_bounds__(256) void k_matmul(const float* __restrict__ xin,
                                                const float* __restrict__ W,
                                                const float* __restrict__ bprev,
                                                float* __restrict__ xw, int n) {
  __shared__ float sW[64 * 64];
  __shared__ float sx[16 * 64];
  int tid = threadIdx.x;
  int tx = tid & 63, ty = tid >> 6;
  const float4* W4 = (const float4*)W;
  float4* sW4 = (float4*)sW;
#pragma unroll
  for (int k = 0; k < 4; k++) sW4[k * 256 + tid] = W4[k * 256 + tid];
  long base = (long)blockIdx.x * 16;
  {
    int r = tid >> 4, c4 = tid & 15;
    long row = base + r;
    float4 v = make_float4(0.f, 0.f, 0.f, 0.f);
    if (row < n) v = ((const float4*)xin)[row * 16 + c4];
    if (ACT) {
      float4 bb = ((const float4*)bprev)[c4];
      v.x = fmaxf(v.x + bb.x, 0.f);
      v.y = fmaxf(v.y + bb.y, 0.f);
      v.z = fmaxf(v.z + bb.z, 0.f);
      v.w = fmaxf(v.w + bb.w, 0.f);
    }
    ((float4*)sx)[tid] = v;
  }
  __syncthreads();
  float acc0 = 0.f, acc1 = 0.f, acc2 = 0.f, acc3 = 0.f;
#pragma unroll
  for (int d = 0; d < 64; d++) {
    float w = sW[d * 64 + tx];
    acc0 += sx[(ty * 4 + 0) * 64 + d] * w;
    acc1 += sx[(ty * 4 + 1) * 64 + d] * w;
    acc2 += sx[(ty * 4 + 2) * 64 + d] * w;
    acc3 += sx[(ty * 4 + 3) * 64 + d] * w;
  }
  long r0 = base + ty * 4;
  if (r0 + 0 < n) xw[(r0 + 0) * 64 + tx] = acc0;
  if (r0 + 1 < n) xw[(r0 + 1) * 64 + tx] = acc1;
  if (r0 + 2 < n) xw[(r0 + 2) * 64 + tx] = acc2;
  if (r0 + 3 < n) xw[(r0 + 3) * 64 + tx] = acc3;
}

// One wave per dst node: agg[t] = xw[t]*dinv[t]^2 + sum_{s in in(t)} xw[s]*dinv[s]*dinv[t]
__global__ __launch_bounds__(256) void k_aggregate(const int* __restrict__ off,
                                                   const int* __restrict__ csrc,
                                                   const float* __restrict__ dinv,
                                                   const float* __restrict__ xw,
                                                   float* __restrict__ agg, int n) {
  int gt = blockIdx.x * blockDim.x + threadIdx.x;
  int t = gt >> 6, lane = gt & 63;
  if (t >= n) return;
  int e0 = off[t], e1 = off[t + 1];
  float di = dinv[t];
  float acc = xw[(long)t * 64 + lane] * (di * di);
  for (int base = e0; base < e1; base += 64) {
    int m = min(64, e1 - base);
    int s_l = 0;
    float w_l = 0.f;
    if (lane < m) {
      s_l = csrc[base + lane];        // coalesced edge fetch
      w_l = dinv[s_l] * di;           // per-edge norm
    }
#pragma unroll 4
    for (int e = 0; e < m; e++) {
      int s = __shfl(s_l, e);
      float w = __shfl(w_l, e);
      acc += xw[(long)s * 64 + lane] * w;   // 256B coalesced row gather
    }
  }
  agg[(long)t * 64 + lane] = acc;
}

// batch is sorted: per-wave register segment reduction, flush on boundary.
__global__ __launch_bounds__(256) void k_pool(const float* __restrict__ x,
                                              const float* __restrict__ b,
                                              const int* __restrict__ batch,
                                              float* __restrict__ hsum,
                                              float* __restrict__ hmax,
                                              int* __restrict__ cntg, int n) {
  int wid = (blockIdx.x * blockDim.x + threadIdx.x) >> 6;
  int lane = threadIdx.x & 63;
  int i0 = wid * 64;
  if (i0 >= n) return;
  int i1 = min(i0 + 64, n);
  float bb = b[lane];
  int batch_l = (i0 + lane < n) ? batch[i0 + lane] : 0;  // coalesced preload
  float gsum = 0.f, gmax = 0.f;
  int cur = __shfl(batch_l, 0);
  int c = 0;
  for (int i = i0; i < i1; i++) {
    int g = __shfl(batch_l, i - i0);
    if (g != cur) {                    // wave-uniform branch
      atomicAdd(&hsum[cur * 64 + lane], gsum);
      atomicMax((int*)&hmax[cur * 64 + lane], __float_as_int(gmax));
      if (lane == 0) atomicAdd(&cntg[cur], c);
      gsum = 0.f; gmax = 0.f; c = 0; cur = g;
    }
    float v = fmaxf(x[(long)i * 64 + lane] + bb, 0.0f);
    gsum += v;
    gmax = fmaxf(gmax, v);
    c++;
  }
  atomicAdd(&hsum[cur * 64 + lane], gsum);
  atomicMax((int*)&hmax[cur * 64 + lane], __float_as_int(gmax));
  if (lane == 0) atomicAdd(&cntg[cur], c);
}

// one block (64 threads) per graph: logits = relu(h@Wc1+bc1)@Wc2+bc2
__global__ __launch_bounds__(64) void k_cls(const float* __restrict__ hsum,
                                            const float* __restrict__ hmax,
                                            const int* __restrict__ cnt,
                                            const float* __restrict__ Wc1,
                                            const float* __restrict__ bc1,
                                            const float* __restrict__ Wc2,
                                            const float* __restrict__ bc2,
                                            float* __restrict__ out) {
  __shared__ float h[128];
  __shared__ float hid[64];
  int g = blockIdx.x, j = threadIdx.x;
  int c = cnt[g];
  float cf = (float)(c > 0 ? c : 1);
  h[j] = hsum[g * 64 + j] / cf;
  h[64 + j] = hmax[g * 64 + j];
  __syncthreads();
  float acc = bc1[j];
  for (int k = 0; k < 128; k++) acc += h[k] * Wc1[k * 64 + j];
  hid[j] = fmaxf(acc, 0.f);
  __syncthreads();
  if (j < 2) {
    float a = bc2[j];
    for (int k = 0; k < 64; k++) a += hid[k] * Wc2[k * 2 + j];
    out[g * 2 + j] = a;
  }
}

extern "C" void kernel_launch(void* const* d_in, const int* in_sizes, int n_in,
                              void* d_out, int out_size, void* d_ws, size_t ws_size,
                              hipStream_t stream) {
  const int N = in_sizes[0];
  const int E = in_sizes[1] / 2;
  const int G = out_size / 2;

  const int* tok   = (const int*)d_in[0];
  const int* ei    = (const int*)d_in[1];
  const int* batch = (const int*)d_in[2];
  const float* emb = (const float*)d_in[3];
  const float* W0 = (const float*)d_in[4];  const float* b0 = (const float*)d_in[5];
  const float* W1 = (const float*)d_in[6];  const float* b1 = (const float*)d_in[7];
  const float* W2 = (const float*)d_in[8];  const float* b2 = (const float*)d_in[9];
  const float* Wc1 = (const float*)d_in[10]; const float* bc1 = (const float*)d_in[11];
  const float* Wc2 = (const float*)d_in[12]; const float* bc2 = (const float*)d_in[13];
  const int* srcp = ei;
  const int* dstp = ei + E;

  // ---- workspace carve-up (all 4-byte elems) ----
  int* cnt    = (int*)d_ws;                      // N
  int* excl   = cnt + N;                         // N (local-excl, then cursor)
  int* bsum   = excl + N;                        // 512
  int* off    = bsum + 512;                      // N+1
  int* csrc   = off + N + 1;                     // E
  float* dinv = (float*)(csrc + E);              // N
  float* bufA = dinv + N;                        // N*64
  float* bufB = bufA + (size_t)N * 64;           // N*64
  float* bufC = bufB + (size_t)N * 64;           // N*64
  float* hsum = bufC + (size_t)N * 64;           // G*64
  float* hmax = hsum + (size_t)G * 64;           // G*64
  int*   cntg = (int*)(hmax + (size_t)G * 64);   // G

  auto cdiv = [](long a, long b) { return (int)((a + b - 1) / b); };
  const int NB = cdiv(N, 256);   // scan blocks (must be <= 512; N<=131072)

  // ---- degree histogram + dinv + CSR build ----
  k_zero<<<cdiv(N, 256), 256, 0, stream>>>((float*)cnt, N);
  k_degcount<<<cdiv(E, 256), 256, 0, stream>>>(dstp, cnt, E);
  k_dinv<<<cdiv(N, 256), 256, 0, stream>>>(cnt, dinv, N);
  k_scan1<<<NB, 256, 0, stream>>>(cnt, excl, bsum, N);
  k_scan2<<<1, 512, 0, stream>>>(bsum, NB);
  k_scan3<<<NB, 256, 0, stream>>>(excl, bsum, off, N, E);
  k_place<<<cdiv(E, 256), 256, 0, stream>>>(srcp, dstp, excl, csrc, E);

  // ---- embedding gather ----
  k_embed<<<cdiv((long)N * 16, 256), 256, 0, stream>>>(tok, emb, bufA, N);

  // ---- 3 GCN layers (matmul + gather-aggregate; bias+relu fused forward) ----
  k_matmul<false><<<cdiv(N, 16), 256, 0, stream>>>(bufA, W0, nullptr, bufB, N);
  k_aggregate<<<cdiv((long)N * 64, 256), 256, 0, stream>>>(off, csrc, dinv, bufB, bufC, N);

  k_matmul<true><<<cdiv(N, 16), 256, 0, stream>>>(bufC, W1, b0, bufA, N);
  k_aggregate<<<cdiv((long)N * 64, 256), 256, 0, stream>>>(off, csrc, dinv, bufA, bufB, N);

  k_matmul<true><<<cdiv(N, 16), 256, 0, stream>>>(bufB, W2, b1, bufC, N);
  k_aggregate<<<cdiv((long)N * 64, 256), 256, 0, stream>>>(off, csrc, dinv, bufC, bufA, N);

  // ---- pooling (relu+b2 fused) ----
  k_zero<<<cdiv((long)G * 129, 256), 256, 0, stream>>>(hsum, (long)G * 129);
  k_pool<<<cdiv(N, 256), 256, 0, stream>>>(bufA, b2, batch, hsum, hmax, cntg, N);

  // ---- classifier head ----
  k_cls<<<G, 64, 0, stream>>>(hsum, hmax, cntg, Wc1, bc1, Wc2, bc2, (float*)d_out);
}

// Round 3
// 732.691 us; speedup vs baseline: 2.4093x; 1.1324x over previous
//
#include <hip/hip_runtime.h>
#include <math.h>

// ---------------------------------------------------------------------------
// DevignLite: 3-layer GCN + mean/max pool + MLP head.  All fp32.
// N=100000 nodes, E=1600000 edges, D=64, G=256 graphs.
// Round 2: single-writer CSR build (kills the 105MB write amplification seen
// in k_place: multi-XCD partial-line scatter).  Two-level bucket sort:
//   k_chist/k_cscan: coarse histogram/scan of dst>>9 (196 buckets)
//   k_part: block-exclusive slice claims -> pair scatter, 1 writer per line
//   k_bplace: per-bucket LDS hist+scan -> off/dinv/csrc (replaces degcount +
//             3 scan kernels + global atomic histogram)
// Plus: embedding fused into matmul0; xw pre-scaled by dinv[row] so the
// aggregate inner loop is a pure row add.
// ---------------------------------------------------------------------------

#define BKT_LOG 9
#define BKT (1 << BKT_LOG)   // 512 nodes per coarse bucket
#define CHUNK 2048           // edges per k_part block (8 per thread)

__global__ void k_zero(float* p, long n) {
  long i = (long)blockIdx.x * blockDim.x + threadIdx.x;
  if (i < n) p[i] = 0.0f;
}

// coarse histogram of dst >> BKT_LOG
__global__ __launch_bounds__(256) void k_chist(const int* __restrict__ dst,
                                               int* __restrict__ chist, int E, int B) {
  __shared__ int h[256];
  h[threadIdx.x] = 0;
  __syncthreads();
  for (long e = (long)blockIdx.x * blockDim.x + threadIdx.x; e < E;
       e += (long)gridDim.x * blockDim.x)
    atomicAdd(&h[dst[e] >> BKT_LOG], 1);
  __syncthreads();
  if (threadIdx.x < B && h[threadIdx.x]) atomicAdd(&chist[threadIdx.x], h[threadIdx.x]);
}

// exclusive scan of chist[B] -> cbase[B+1]; cursor copy -> gcur
__global__ __launch_bounds__(256) void k_cscan(const int* __restrict__ chist,
                                               int* __restrict__ cbase,
                                               int* __restrict__ gcur, int E, int B) {
  __shared__ int s[256];
  int v = (threadIdx.x < B) ? chist[threadIdx.x] : 0;
  s[threadIdx.x] = v;
  __syncthreads();
  for (int d = 1; d < 256; d <<= 1) {
    int t = (threadIdx.x >= (unsigned)d) ? s[threadIdx.x - d] : 0;
    __syncthreads();
    s[threadIdx.x] += t;
    __syncthreads();
  }
  if (threadIdx.x < B) {
    int ex = s[threadIdx.x] - v;
    cbase[threadIdx.x] = ex;
    gcur[threadIdx.x] = ex;
  }
  if (threadIdx.x == B) cbase[B] = E;
}

// partition pass: scatter (src,dst) pairs into coarse-bucket order.
// Each block claims exclusive contiguous slices per bucket -> single writer
// per cache line -> full-line writebacks.
__global__ __launch_bounds__(256) void k_part(const int* __restrict__ src,
                                              const int* __restrict__ dst,
                                              int* __restrict__ gcur,
                                              int2* __restrict__ ebuf, int E, int B) {
  __shared__ int h[256], base[256], cur[256];
  long c0 = (long)blockIdx.x * CHUNK;
  int m = (int)min((long)CHUNK, (long)E - c0);
  int sreg[8], dreg[8];
  h[threadIdx.x] = 0;
  __syncthreads();
#pragma unroll
  for (int j = 0; j < 8; j++) {
    int idx = threadIdx.x + j * 256;
    if (idx < m) {
      sreg[j] = src[c0 + idx];
      dreg[j] = dst[c0 + idx];
      atomicAdd(&h[dreg[j] >> BKT_LOG], 1);
    }
  }
  __syncthreads();
  if (threadIdx.x < B && h[threadIdx.x])
    base[threadIdx.x] = atomicAdd(&gcur[threadIdx.x], h[threadIdx.x]);
  cur[threadIdx.x] = 0;
  __syncthreads();
#pragma unroll
  for (int j = 0; j < 8; j++) {
    int idx = threadIdx.x + j * 256;
    if (idx < m) {
      int k = dreg[j] >> BKT_LOG;
      int p = base[k] + atomicAdd(&cur[k], 1);
      ebuf[p] = make_int2(sreg[j], dreg[j]);
    }
  }
}

// per-bucket: node histogram + scan in LDS -> off/dinv, then place csrc.
// One workgroup per bucket -> csrc region single-writer.
__global__ __launch_bounds__(512) void k_bplace(const int2* __restrict__ ebuf,
                                                const int* __restrict__ cbase,
                                                int* __restrict__ off,
                                                int* __restrict__ csrc,
                                                float* __restrict__ dinv,
                                                int N, int E) {
  __shared__ int s[512];
  __shared__ int cur[512];
  int b = blockIdx.x, tid = threadIdx.x;
  int n0 = b << BKT_LOG;
  int nn = min(BKT, N - n0);
  int e0 = cbase[b], e1 = cbase[b + 1];
  s[tid] = 0;
  __syncthreads();
  for (int e = e0 + tid; e < e1; e += 512) atomicAdd(&s[ebuf[e].y - n0], 1);
  __syncthreads();
  int deg = s[tid];
  for (int d = 1; d < 512; d <<= 1) {
    int t = (tid >= d) ? s[tid - d] : 0;
    __syncthreads();
    s[tid] += t;
    __syncthreads();
  }
  int excl = s[tid] - deg;
  if (tid < nn) {
    off[n0 + tid] = e0 + excl;
    dinv[n0 + tid] = 1.0f / sqrtf((float)(1 + deg));
  }
  cur[tid] = excl;
  __syncthreads();
  for (int e = e0 + tid; e < e1; e += 512) {
    int2 p = ebuf[e];
    int pos = e0 + atomicAdd(&cur[p.y - n0], 1);
    csrc[pos] = p.x;
  }
  if (b == 0 && tid == 0) off[N] = E;
}

// xw[row] = act(xin[row]) @ W * dinv[row]
// EMB: xin = emb_table[tok[row]]; ACT: relu(xin + bprev).
template <bool EMB, bool ACT>
__global__ __launch_bounds__(256) void k_matmul(const float* __restrict__ xin,
                                                const int* __restrict__ tok,
                                                const float* __restrict__ emb,
                                                const float* __restrict__ W,
                                                const float* __restrict__ bprev,
                                                const float* __restrict__ dinv,
                                                float* __restrict__ xw, int n) {
  __shared__ float sW[64 * 64];
  __shared__ float sx[16 * 64];
  int tid = threadIdx.x;
  int tx = tid & 63, ty = tid >> 6;
  const float4* W4 = (const float4*)W;
  float4* sW4 = (float4*)sW;
#pragma unroll
  for (int k = 0; k < 4; k++) sW4[k * 256 + tid] = W4[k * 256 + tid];
  long base = (long)blockIdx.x * 16;
  {
    int r = tid >> 4, c4 = tid & 15;
    long row = base + r;
    float4 v = make_float4(0.f, 0.f, 0.f, 0.f);
    if (row < n) {
      if (EMB) {
        long t = tok[row];
        v = ((const float4*)emb)[t * 16 + c4];
      } else {
        v = ((const float4*)xin)[row * 16 + c4];
      }
    }
    if (ACT) {
      float4 bb = ((const float4*)bprev)[c4];
      v.x = fmaxf(v.x + bb.x, 0.f);
      v.y = fmaxf(v.y + bb.y, 0.f);
      v.z = fmaxf(v.z + bb.z, 0.f);
      v.w = fmaxf(v.w + bb.w, 0.f);
    }
    ((float4*)sx)[tid] = v;
  }
  __syncthreads();
  float acc0 = 0.f, acc1 = 0.f, acc2 = 0.f, acc3 = 0.f;
#pragma unroll
  for (int d = 0; d < 64; d++) {
    float w = sW[d * 64 + tx];
    acc0 += sx[(ty * 4 + 0) * 64 + d] * w;
    acc1 += sx[(ty * 4 + 1) * 64 + d] * w;
    acc2 += sx[(ty * 4 + 2) * 64 + d] * w;
    acc3 += sx[(ty * 4 + 3) * 64 + d] * w;
  }
  long r0 = base + ty * 4;
  if (r0 + 0 < n) xw[(r0 + 0) * 64 + tx] = acc0 * dinv[r0 + 0];
  if (r0 + 1 < n) xw[(r0 + 1) * 64 + tx] = acc1 * dinv[r0 + 1];
  if (r0 + 2 < n) xw[(r0 + 2) * 64 + tx] = acc2 * dinv[r0 + 2];
  if (r0 + 3 < n) xw[(r0 + 3) * 64 + tx] = acc3 * dinv[r0 + 3];
}

// One wave per dst node: agg[t] = dinv[t] * (xws[t] + sum_{s in in(t)} xws[s])
// (xws rows pre-scaled by dinv[src] in the matmul epilogue)
__global__ __launch_bounds__(256) void k_aggregate(const int* __restrict__ off,
                                                   const int* __restrict__ csrc,
                                                   const float* __restrict__ dinv,
                                                   const float* __restrict__ xws,
                                                   float* __restrict__ agg, int n) {
  int gt = blockIdx.x * blockDim.x + threadIdx.x;
  int t = gt >> 6, lane = gt & 63;
  if (t >= n) return;
  int e0 = off[t], e1 = off[t + 1];
  float acc = xws[(long)t * 64 + lane];
  for (int base = e0; base < e1; base += 64) {
    int m = min(64, e1 - base);
    int s_l = (lane < m) ? csrc[base + lane] : 0;
#pragma unroll 4
    for (int e = 0; e < m; e++) {
      int s = __shfl(s_l, e);
      acc += xws[(long)s * 64 + lane];
    }
  }
  agg[(long)t * 64 + lane] = acc * dinv[t];
}

// batch is sorted: per-wave register segment reduction, flush on boundary.
__global__ __launch_bounds__(256) void k_pool(const float* __restrict__ x,
                                              const float* __restrict__ b,
                                              const int* __restrict__ batch,
                                              float* __restrict__ hsum,
                                              float* __restrict__ hmax,
                                              int* __restrict__ cntg, int n) {
  int wid = (blockIdx.x * blockDim.x + threadIdx.x) >> 6;
  int lane = threadIdx.x & 63;
  int i0 = wid * 64;
  if (i0 >= n) return;
  int i1 = min(i0 + 64, n);
  float bb = b[lane];
  int batch_l = (i0 + lane < n) ? batch[i0 + lane] : 0;
  float gsum = 0.f, gmax = 0.f;
  int cur = __shfl(batch_l, 0);
  int c = 0;
  for (int i = i0; i < i1; i++) {
    int g = __shfl(batch_l, i - i0);
    if (g != cur) {
      atomicAdd(&hsum[cur * 64 + lane], gsum);
      atomicMax((int*)&hmax[cur * 64 + lane], __float_as_int(gmax));
      if (lane == 0) atomicAdd(&cntg[cur], c);
      gsum = 0.f; gmax = 0.f; c = 0; cur = g;
    }
    float v = fmaxf(x[(long)i * 64 + lane] + bb, 0.0f);
    gsum += v;
    gmax = fmaxf(gmax, v);
    c++;
  }
  atomicAdd(&hsum[cur * 64 + lane], gsum);
  atomicMax((int*)&hmax[cur * 64 + lane], __float_as_int(gmax));
  if (lane == 0) atomicAdd(&cntg[cur], c);
}

// one block (64 threads) per graph: logits = relu(h@Wc1+bc1)@Wc2+bc2
__global__ __launch_bounds__(64) void k_cls(const float* __restrict__ hsum,
                                            const float* __restrict__ hmax,
                                            const int* __restrict__ cnt,
                                            const float* __restrict__ Wc1,
                                            const float* __restrict__ bc1,
                                            const float* __restrict__ Wc2,
                                            const float* __restrict__ bc2,
                                            float* __restrict__ out) {
  __shared__ float h[128];
  __shared__ float hid[64];
  int g = blockIdx.x, j = threadIdx.x;
  int c = cnt[g];
  float cf = (float)(c > 0 ? c : 1);
  h[j] = hsum[g * 64 + j] / cf;
  h[64 + j] = hmax[g * 64 + j];
  __syncthreads();
  float acc = bc1[j];
  for (int k = 0; k < 128; k++) acc += h[k] * Wc1[k * 64 + j];
  hid[j] = fmaxf(acc, 0.f);
  __syncthreads();
  if (j < 2) {
    float a = bc2[j];
    for (int k = 0; k < 64; k++) a += hid[k] * Wc2[k * 2 + j];
    out[g * 2 + j] = a;
  }
}

extern "C" void kernel_launch(void* const* d_in, const int* in_sizes, int n_in,
                              void* d_out, int out_size, void* d_ws, size_t ws_size,
                              hipStream_t stream) {
  const int N = in_sizes[0];
  const int E = in_sizes[1] / 2;
  const int G = out_size / 2;
  const int B = (N + BKT - 1) >> BKT_LOG;   // coarse buckets (196 for N=100000)

  const int* tok   = (const int*)d_in[0];
  const int* ei    = (const int*)d_in[1];
  const int* batch = (const int*)d_in[2];
  const float* emb = (const float*)d_in[3];
  const float* W0 = (const float*)d_in[4];  const float* b0 = (const float*)d_in[5];
  const float* W1 = (const float*)d_in[6];  const float* b1 = (const float*)d_in[7];
  const float* W2 = (const float*)d_in[8];  const float* b2 = (const float*)d_in[9];
  const float* Wc1 = (const float*)d_in[10]; const float* bc1 = (const float*)d_in[11];
  const float* Wc2 = (const float*)d_in[12]; const float* bc2 = (const float*)d_in[13];
  const int* srcp = ei;
  const int* dstp = ei + E;

  // ---- workspace carve-up (4-byte units; keep segment starts even) ----
  int* off    = (int*)d_ws;                      // N+2 (pad)
  int* csrc   = off + N + 2;                     // E
  float* dinv = (float*)(csrc + E);              // N
  int* chist  = (int*)(dinv + N);                // 256
  int* cbase  = chist + 256;                     // 256 (B+1 used)
  int* gcur   = cbase + 256;                     // 256
  float* bufA = (float*)(gcur + 256);            // N*64
  float* bufB = bufA + (size_t)N * 64;           // N*64
  float* bufC = bufB + (size_t)N * 64;           // N*64
  int2* ebuf  = (int2*)bufC;                     // E pairs (dead before bufC use)
  float* hsum = bufC + (size_t)N * 64;           // G*64
  float* hmax = hsum + (size_t)G * 64;           // G*64
  int*   cntg = (int*)(hmax + (size_t)G * 64);   // G

  auto cdiv = [](long a, long b) { return (int)((a + b - 1) / b); };

  // ---- CSR build (single-writer placement) ----
  k_zero<<<1, 256, 0, stream>>>((float*)chist, 256);
  k_chist<<<cdiv(E, CHUNK), 256, 0, stream>>>(dstp, chist, E, B);
  k_cscan<<<1, 256, 0, stream>>>(chist, cbase, gcur, E, B);
  k_part<<<cdiv(E, CHUNK), 256, 0, stream>>>(srcp, dstp, gcur, ebuf, E, B);
  k_bplace<<<B, 512, 0, stream>>>(ebuf, cbase, off, csrc, dinv, N, E);

  // ---- 3 GCN layers (embed fused into mm0; bias+relu fused forward) ----
  k_matmul<true, false><<<cdiv(N, 16), 256, 0, stream>>>(nullptr, tok, emb, W0, nullptr, dinv, bufA, N);
  k_aggregate<<<cdiv((long)N * 64, 256), 256, 0, stream>>>(off, csrc, dinv, bufA, bufB, N);

  k_matmul<false, true><<<cdiv(N, 16), 256, 0, stream>>>(bufB, nullptr, nullptr, W1, b0, dinv, bufC, N);
  k_aggregate<<<cdiv((long)N * 64, 256), 256, 0, stream>>>(off, csrc, dinv, bufC, bufA, N);

  k_matmul<false, true><<<cdiv(N, 16), 256, 0, stream>>>(bufA, nullptr, nullptr, W2, b1, dinv, bufB, N);
  k_aggregate<<<cdiv((long)N * 64, 256), 256, 0, stream>>>(off, csrc, dinv, bufB, bufC, N);

  // ---- pooling (relu+b2 fused) ----
  k_zero<<<cdiv((long)G * 129, 256), 256, 0, stream>>>(hsum, (long)G * 129);
  k_pool<<<cdiv(N, 256), 256, 0, stream>>>(bufC, b2, batch, hsum, hmax, cntg, N);

  // ---- classifier head ----
  k_cls<<<G, 64, 0, stream>>>(hsum, hmax, cntg, Wc1, bc1, Wc2, bc2, (float*)d_out);
}